// Round 1
// baseline (503.734 us; speedup 1.0000x reference)
//
#include <hip/hip_runtime.h>
#include <hip/hip_fp16.h>

// Problem constants (fixed by the reference's setup_inputs)
#define NB 2          // batch
#define NN 262144     // events per batch (2^18)
#define ND 10         // temporal bins (base)
#define NR 11         // warp references (base + 1)
#define HH 256
#define WW 256
#define HWSZ 65536
#define SROWS 16      // rows per y-strip
#define NSTRIP 16     // 256 / SROWS
#define PLANE (SROWS * WW)   // 4096 floats per (pol, e/t) plane
#define EPSF 1e-9f

// ws layout (18.25 MB -- under the 23.07 MB proven good in R1/R2):
//   float4 ev[2*NB*NN]  : [2i]=(ax,ay,dx,dy)  warped pos at ref r = (ax+r*dx, ay+r*dy)
//                         [2i+1]=(ts,p,-,-)   one 32B record -> one cacheline on accept
//   uint   ytest[NB*NN] : packed (f16(ay) | f16(dy)<<16) -- 2 MB, L2-resident reject stream
//   float  accum[64]    : (sumsq, inside) per (b,r)
//
// R4 theory: cm_scan was streaming 16 B/event * 352 blocks = 1.4 GB from LLC just
// to reject 15/16 of events per strip. The y-decision needs only (ay, dy): pack
// them f16 (4 B/event, 2 MB total -> every XCD L2 caches it). f16 error <= 0.34
// rows; reject window widened to [ty0-2, tyhi+1) and accepted candidates re-test
// exactly in f32 -> bitwise-identical accumulation vs baseline.
// Also: LDS planes split (iwe/iwt separate) so atomics use all 32 banks.

__global__ __launch_bounds__(256) void cm_prep(
    const float* __restrict__ events,
    const float* __restrict__ flow,
    float4* __restrict__ ev,
    unsigned* __restrict__ ytest)
{
    int gid = blockIdx.x * 256 + threadIdx.x;
    if (gid >= NB * NN) return;
    int b = gid >> 18;

    const float* e = events + (size_t)gid * 5;
    float x  = e[0];
    float y  = e[1];
    float t  = e[2];
    float ts = e[3];
    float p  = e[4];

    int zi = (int)floorf(t);
    zi = zi < 0 ? 0 : (zi > ND - 1 ? ND - 1 : zi);

    int x0 = (int)floorf(x);
    x0 = x0 < 0 ? 0 : (x0 > WW - 2 ? WW - 2 : x0);
    int y0 = (int)floorf(y);
    y0 = y0 < 0 ? 0 : (y0 > HH - 2 ? HH - 2 : y0);
    float fx = fminf(fmaxf(x - (float)x0, 0.0f), 1.0f);
    float fy = fminf(fmaxf(y - (float)y0, 0.0f), 1.0f);

    const float2* f2 = (const float2*)flow + ((size_t)b * ND + zi) * HWSZ;
    float2 f00 = f2[y0 * WW + x0];
    float2 f01 = f2[y0 * WW + x0 + 1];
    float2 f10 = f2[(y0 + 1) * WW + x0];
    float2 f11 = f2[(y0 + 1) * WW + x0 + 1];
    float w00 = (1.0f - fx) * (1.0f - fy);
    float w01 = fx * (1.0f - fy);
    float w10 = (1.0f - fx) * fy;
    float w11 = fx * fy;
    float flx = w00 * f00.x + w01 * f01.x + w10 * f10.x + w11 * f11.x;
    float fly = w00 * f00.y + w01 * f01.y + w10 * f10.y + w11 * f11.y;

    float ax = fmaf(-t, flx, x);
    float ay = fmaf(-t, fly, y);

    ev[2 * (size_t)gid]     = make_float4(ax, ay, flx, fly);
    ev[2 * (size_t)gid + 1] = make_float4(ts, p, 0.0f, 0.0f);

    unsigned short hay = __half_as_ushort(__float2half(ay));
    unsigned short hdy = __half_as_ushort(__float2half(fly));
    ytest[gid] = (unsigned)hay | ((unsigned)hdy << 16);
}

__global__ __launch_bounds__(512) void cm_scan(
    const float4* __restrict__ ev,
    const unsigned* __restrict__ ytest,
    float* __restrict__ accum)
{
    // plane-split: [pol][iwe|iwt][SROWS*WW] -- 64 KB, atomics hit all 32 banks
    __shared__ float acc[4 * PLANE];

    int bi  = blockIdx.x;                  // 0 .. NB*NR*NSTRIP-1
    int b   = bi / (NR * NSTRIP);
    int rem = bi - b * (NR * NSTRIP);
    int r   = rem >> 4;
    int st  = rem & 15;
    int ty0  = st * SROWS;
    int tyhi = ty0 + SROWS;                // exclusive

    for (int i = threadIdx.x; i < 4 * PLANE; i += 512)
        acc[i] = 0.0f;
    __syncthreads();

    const float rf  = (float)r;
    const float ylo = (float)ty0 - 2.0f;   // f16 round-trip err <= 0.34 < margin
    const float yhi = (float)tyhi + 1.0f;
    const int base  = b * NN;
    const uint4* yt4 = (const uint4*)(ytest + base);

    for (int i = threadIdx.x; i < NN / 4; i += 512) {
        uint4 q = yt4[i];
        unsigned qa[4] = { q.x, q.y, q.z, q.w };
        #pragma unroll
        for (int k = 0; k < 4; ++k) {
            unsigned u = qa[k];
            float ayh = __half2float(__ushort_as_half((unsigned short)(u & 0xffffu)));
            float dyh = __half2float(__ushort_as_half((unsigned short)(u >> 16)));
            float wyh = fmaf(rf, dyh, ayh);
            if (!(wyh >= ylo && wyh < yhi)) continue;

            size_t ei = (size_t)(base + 4 * i + k) * 2;
            float4 ea = ev[ei];
            float wx = fmaf(rf, ea.z, ea.x);
            float wy = fmaf(rf, ea.w, ea.y);
            float fwx = floorf(wx);
            float fwy = floorf(wy);
            int xi = (int)fwx;
            int yi = (int)fwy;
            if (yi + 1 < ty0 || yi >= tyhi || xi + 1 < 0 || xi >= WW) continue;

            float4 eb = ev[ei + 1];
            float axf = wx - fwx;
            float ayf = wy - fwy;
            float ts = eb.x;
            int pi = eb.y != 0.0f ? 1 : 0;
            float* ap = acc + pi * (2 * PLANE);

            float c00 = (1.0f - axf) * (1.0f - ayf);
            float c01 = axf * (1.0f - ayf);
            float c10 = (1.0f - axf) * ayf;
            float c11 = axf * ayf;

            #define CM_CORNER(XI, YI, WV)                                    \
                if ((XI) >= 0 && (XI) < WW && (YI) >= ty0 && (YI) < tyhi) {  \
                    int li = ((YI) - ty0) * WW + (XI);                       \
                    atomicAdd(ap + li,         (WV));                        \
                    atomicAdd(ap + PLANE + li, (WV) * ts);                   \
                }
            CM_CORNER(xi,     yi,     c00)
            CM_CORNER(xi + 1, yi,     c01)
            CM_CORNER(xi,     yi + 1, c10)
            CM_CORNER(xi + 1, yi + 1, c11)
            #undef CM_CORNER
        }
    }
    __syncthreads();

    // fused reduction: this block exclusively owns its strip for both
    // polarities -> sum((iwt/(iwe+eps))^2) and count(iwe0+iwe1 > 0)
    float ss = 0.0f, ins = 0.0f;
    for (int i = threadIdx.x; i < PLANE; i += 512) {
        float e0 = acc[i];
        float t0 = acc[PLANE + i];
        float e1 = acc[2 * PLANE + i];
        float t1 = acc[3 * PLANE + i];
        float a0 = t0 / (e0 + EPSF);
        float a1 = t1 / (e1 + EPSF);
        ss += a0 * a0 + a1 * a1;
        ins += ((e0 + e1) > 0.0f) ? 1.0f : 0.0f;
    }
    #pragma unroll
    for (int off = 32; off > 0; off >>= 1) {
        ss  += __shfl_down(ss, off, 64);
        ins += __shfl_down(ins, off, 64);
    }
    __syncthreads();  // all LDS reads done before reusing acc[] for partials
    int lane = threadIdx.x & 63;
    int wv = threadIdx.x >> 6;
    if (lane == 0) { acc[2 * wv] = ss; acc[2 * wv + 1] = ins; }
    __syncthreads();
    if (threadIdx.x == 0) {
        float tss = 0.0f, tin = 0.0f;
        #pragma unroll
        for (int w = 0; w < 8; ++w) { tss += acc[2 * w]; tin += acc[2 * w + 1]; }
        int br = b * NR + r;
        atomicAdd(&accum[br * 2],     tss);  // 704 total atomics -- negligible
        atomicAdd(&accum[br * 2 + 1], tin);
    }
}

__global__ void cm_final(const float* __restrict__ accum, float* __restrict__ out)
{
    int i = threadIdx.x;
    if (i < NB * NR) {
        out[i] = accum[i * 2] / (accum[i * 2 + 1] + EPSF);
    }
}

extern "C" void kernel_launch(void* const* d_in, const int* in_sizes, int n_in,
                              void* d_out, int out_size, void* d_ws, size_t ws_size,
                              hipStream_t stream) {
    const float* events = (const float*)d_in[0];
    const float* flow   = (const float*)d_in[1];

    char* ws = (char*)d_ws;
    float4* ev = (float4*)ws;
    size_t ev_bytes = (size_t)NB * NN * 2 * sizeof(float4);   // 16,777,216
    unsigned* ytest = (unsigned*)(ws + ev_bytes);
    size_t yt_bytes = (size_t)NB * NN * sizeof(unsigned);     // 2,097,152
    float* accum = (float*)(ws + ev_bytes + yt_bytes);
    size_t accum_bytes = 256;                                 // 44 floats, padded

    hipMemsetAsync(accum, 0, accum_bytes, stream);

    cm_prep<<<(NB * NN + 255) / 256, 256, 0, stream>>>(events, flow, ev, ytest);

    cm_scan<<<NB * NR * NSTRIP, 512, 0, stream>>>(ev, ytest, accum);

    cm_final<<<1, 64, 0, stream>>>(accum, (float*)d_out);
}

// Round 2
// 372.105 us; speedup vs baseline: 1.3537x; 1.3537x over previous
//
#include <hip/hip_runtime.h>

// Problem constants (fixed by the reference's setup_inputs)
#define NB 2          // batch
#define NN 262144     // events per batch (2^18)
#define ND 10         // temporal bins (base)
#define NR 11         // warp references (base + 1)
#define HH 256
#define WW 256
#define HWSZ 65536
#define SROWS 8       // rows per y-strip
#define NSTRIP 32     // 256 / SROWS
#define PLANE (SROWS * WW)   // 2048 floats per (pol, e/t) plane
#define NWAVE 8
#define QCAP 192      // per-wave queue: qn<=63 before a pair, +128 max burst
#define EPSF 1e-9f

// ws layout (21.5 MB -- under the 23.07 MB proven good):
//   float4 ev[2*NB*NN]        : [2i]=(ax,ay,dx,dy), [2i+1]=(ts,p,-,-)  (32 B, one line)
//   uchar  ystrip[NB][NR][NN] : strip-id byte per (event, r):
//                               bits0-6 = strip of first valid row, bit7 = straddles
//                               next strip, 0x7F = no corner in range (never matches)
//   float  accum[64]          : (sumsq, inside) per (b,r)
//
// R1 lesson (counters): scan was LATENCY/DIVERGENCE-bound (VALUBusy 24.6%, HBM 1.8%,
// occ 28%) -- the ~50-instr accepted path ran at wave level for ~98% of event-groups
// with ~6% lane density, each paying a dependent scattered ev load at 2 blocks/CU.
// Fix: exact byte prefilter (built with bit-identical fmas in prep) + per-wave
// ballot-compacted LDS queue -> accepted path runs dense (64 useful lanes), and
// SROWS=8 gives 32KB planes -> 4 blocks/CU, 704 blocks (9% imbalance vs 45%).

__global__ __launch_bounds__(256) void cm_prep(
    const float* __restrict__ events,
    const float* __restrict__ flow,
    float4* __restrict__ ev,
    unsigned char* __restrict__ ystrip)
{
    int gid = blockIdx.x * 256 + threadIdx.x;
    if (gid >= NB * NN) return;
    int b = gid >> 18;
    int li = gid & (NN - 1);

    const float* e = events + (size_t)gid * 5;
    float x  = e[0];
    float y  = e[1];
    float t  = e[2];
    float ts = e[3];
    float p  = e[4];

    int zi = (int)floorf(t);
    zi = zi < 0 ? 0 : (zi > ND - 1 ? ND - 1 : zi);

    int x0 = (int)floorf(x);
    x0 = x0 < 0 ? 0 : (x0 > WW - 2 ? WW - 2 : x0);
    int y0 = (int)floorf(y);
    y0 = y0 < 0 ? 0 : (y0 > HH - 2 ? HH - 2 : y0);
    float fx = fminf(fmaxf(x - (float)x0, 0.0f), 1.0f);
    float fy = fminf(fmaxf(y - (float)y0, 0.0f), 1.0f);

    const float2* f2 = (const float2*)flow + ((size_t)b * ND + zi) * HWSZ;
    float2 f00 = f2[y0 * WW + x0];
    float2 f01 = f2[y0 * WW + x0 + 1];
    float2 f10 = f2[(y0 + 1) * WW + x0];
    float2 f11 = f2[(y0 + 1) * WW + x0 + 1];
    float w00 = (1.0f - fx) * (1.0f - fy);
    float w01 = fx * (1.0f - fy);
    float w10 = (1.0f - fx) * fy;
    float w11 = fx * fy;
    float flx = w00 * f00.x + w01 * f01.x + w10 * f10.x + w11 * f11.x;
    float fly = w00 * f00.y + w01 * f01.y + w10 * f10.y + w11 * f11.y;

    float ax = fmaf(-t, flx, x);
    float ay = fmaf(-t, fly, y);

    ev[2 * (size_t)gid]     = make_float4(ax, ay, flx, fly);
    ev[2 * (size_t)gid + 1] = make_float4(ts, p, 0.0f, 0.0f);

    // exact strip-id byte per r (same fma ordering as cm_scan -> exact filter)
    unsigned char* ysb = ystrip + (size_t)b * NR * NN + li;
    #pragma unroll
    for (int r = 0; r < NR; ++r) {
        float rf = (float)r;
        float wx = fmaf(rf, flx, ax);
        float wy = fmaf(rf, fly, ay);
        int xi = (int)floorf(wx);
        int yi = (int)floorf(wy);
        unsigned byte;
        if (xi + 1 < 0 || xi >= WW || yi + 1 < 0 || yi >= HH) {
            byte = 0x7Fu;  // no corner can land -> matches no strip
        } else {
            int rr = yi < 0 ? 0 : yi;          // first in-range row
            int s0 = rr >> 3;                  // SROWS = 8
            int str = (yi >= 0 && yi + 1 < HH && ((yi >> 3) != ((yi + 1) >> 3))) ? 0x80 : 0;
            byte = (unsigned)s0 | (unsigned)str;
        }
        ysb[(size_t)r * NN] = (unsigned char)byte;
    }
}

__global__ __launch_bounds__(512) void cm_scan(
    const float4* __restrict__ ev,
    const unsigned char* __restrict__ ystrip,
    float* __restrict__ accum)
{
    // plane-split: [pol][iwe|iwt][SROWS*WW] -- 32 KB
    __shared__ float acc[4 * PLANE];
    __shared__ unsigned q[NWAVE][QCAP];    // 6 KB per-wave work queues

    int bi  = blockIdx.x;                  // 0 .. NB*NR*NSTRIP-1
    int b   = bi / (NR * NSTRIP);
    int rem = bi - b * (NR * NSTRIP);
    int r   = rem >> 5;
    int st  = rem & 31;
    int ty0 = st * SROWS;

    for (int i = threadIdx.x; i < 4 * PLANE; i += 512)
        acc[i] = 0.0f;
    __syncthreads();

    const float rf = (float)r;
    const float4* evb = ev + (size_t)b * NN * 2;
    const uint4* ys4 = (const uint4*)(ystrip + ((size_t)b * NR + r) * NN);

    int lane = threadIdx.x & 63;
    int wv   = threadIdx.x >> 6;
    unsigned long long mlt = (1ull << lane) - 1ull;
    unsigned stu = (unsigned)st;
    int qn = 0;

    auto process = [&](unsigned idx) {
        float4 ea = evb[2 * (size_t)idx];
        float4 eb = evb[2 * (size_t)idx + 1];
        float wx = fmaf(rf, ea.z, ea.x);
        float wy = fmaf(rf, ea.w, ea.y);
        float fwx = floorf(wx);
        float fwy = floorf(wy);
        int xi = (int)fwx;
        int yi = (int)fwy;
        float axf = wx - fwx;
        float ayf = wy - fwy;
        float tsv = eb.x;
        int pi = (eb.y != 0.0f) ? 1 : 0;
        float* ap = acc + pi * (2 * PLANE);
        float c00 = (1.0f - axf) * (1.0f - ayf);
        float c01 = axf * (1.0f - ayf);
        float c10 = (1.0f - axf) * ayf;
        float c11 = axf * ayf;
        #define CM_CORNER(XI, YI, WV)                                          \
            if ((XI) >= 0 && (XI) < WW && (YI) >= ty0 && (YI) < ty0 + SROWS) { \
                int liq = ((YI) - ty0) * WW + (XI);                            \
                atomicAdd(ap + liq,         (WV));                             \
                atomicAdd(ap + PLANE + liq, (WV) * tsv);                       \
            }
        CM_CORNER(xi,     yi,     c00)
        CM_CORNER(xi + 1, yi,     c01)
        CM_CORNER(xi,     yi + 1, c10)
        CM_CORNER(xi + 1, yi + 1, c11)
        #undef CM_CORNER
    };

    // each wave owns a contiguous range of 16-event chunks; all 64 lanes always active
    const int CHUNKS = (NN / 16) / NWAVE;  // 2048
    int cbase = wv * CHUNKS;
    for (int j = lane; j < CHUNKS; j += 64) {
        int c = cbase + j;
        uint4 w4 = ys4[c];
        unsigned idx0 = (unsigned)c << 4;
        unsigned words[4] = { w4.x, w4.y, w4.z, w4.w };
        #pragma unroll
        for (int wd = 0; wd < 4; ++wd) {
            unsigned word = words[wd];
            #pragma unroll
            for (int pk = 0; pk < 2; ++pk) {
                #pragma unroll
                for (int kk = 0; kk < 2; ++kk) {
                    int k = pk * 2 + kk;
                    unsigned byte = (word >> (8 * k)) & 0xFFu;
                    unsigned s = byte & 0x7Fu;
                    bool hit = (s == stu) || ((byte & 0x80u) && (s + 1u == stu));
                    unsigned long long m = __ballot(hit);
                    if (m) {
                        int rank = __popcll(m & mlt);
                        if (hit) q[wv][qn + rank] = idx0 + (unsigned)(wd * 4 + k);
                        qn += __popcll(m);
                    }
                }
                while (qn >= 64) {           // dense batch: all 64 lanes useful
                    qn -= 64;
                    process(q[wv][qn + lane]);
                }
            }
        }
    }
    if (lane < qn) process(q[wv][lane]);     // tail (<64 entries, one divergent pass)
    __syncthreads();

    // fused reduction: this block exclusively owns its strip for both polarities
    float ss = 0.0f, ins = 0.0f;
    for (int i = threadIdx.x; i < PLANE; i += 512) {
        float e0 = acc[i];
        float t0 = acc[PLANE + i];
        float e1 = acc[2 * PLANE + i];
        float t1 = acc[3 * PLANE + i];
        float a0 = t0 / (e0 + EPSF);
        float a1 = t1 / (e1 + EPSF);
        ss += a0 * a0 + a1 * a1;
        ins += ((e0 + e1) > 0.0f) ? 1.0f : 0.0f;
    }
    #pragma unroll
    for (int off = 32; off > 0; off >>= 1) {
        ss  += __shfl_down(ss, off, 64);
        ins += __shfl_down(ins, off, 64);
    }
    __syncthreads();  // all LDS reads done before reusing acc[] for partials
    if (lane == 0) { acc[2 * wv] = ss; acc[2 * wv + 1] = ins; }
    __syncthreads();
    if (threadIdx.x == 0) {
        float tss = 0.0f, tin = 0.0f;
        #pragma unroll
        for (int w = 0; w < NWAVE; ++w) { tss += acc[2 * w]; tin += acc[2 * w + 1]; }
        int br = b * NR + r;
        atomicAdd(&accum[br * 2],     tss);  // 1408 total atomics -- negligible
        atomicAdd(&accum[br * 2 + 1], tin);
    }
}

__global__ void cm_final(const float* __restrict__ accum, float* __restrict__ out)
{
    int i = threadIdx.x;
    if (i < NB * NR) {
        out[i] = accum[i * 2] / (accum[i * 2 + 1] + EPSF);
    }
}

extern "C" void kernel_launch(void* const* d_in, const int* in_sizes, int n_in,
                              void* d_out, int out_size, void* d_ws, size_t ws_size,
                              hipStream_t stream) {
    const float* events = (const float*)d_in[0];
    const float* flow   = (const float*)d_in[1];

    char* ws = (char*)d_ws;
    float4* ev = (float4*)ws;
    size_t ev_bytes = (size_t)NB * NN * 2 * sizeof(float4);       // 16,777,216
    unsigned char* ystrip = (unsigned char*)(ws + ev_bytes);
    size_t ys_bytes = (size_t)NB * NR * NN;                       // 5,767,168
    float* accum = (float*)(ws + ev_bytes + ys_bytes);
    size_t accum_bytes = 256;                                     // 44 floats, padded

    hipMemsetAsync(accum, 0, accum_bytes, stream);

    cm_prep<<<(NB * NN + 255) / 256, 256, 0, stream>>>(events, flow, ev, ystrip);

    cm_scan<<<NB * NR * NSTRIP, 512, 0, stream>>>(ev, ystrip, accum);

    cm_final<<<1, 64, 0, stream>>>(accum, (float*)d_out);
}